// Round 13
// baseline (254.869 us; speedup 1.0000x reference)
//
#include <hip/hip_runtime.h>
#include <math.h>

#define BB 4
#define NN 4096

// workspace layout (float offsets)
#define OFF_W0S   0        // 256 fp32: w0*s0 [c][4]
#define OFF_B0F   256      // 64 fp32
#define OFF_B1    320      // 64 fp32
#define OFF_B2    384      // 128 fp32
#define OFF_W1F   512      // 4096 bf16 (2048 floats): W1 B-frags [kb*4+nb][lane][8]
#define OFF_W2F   2560     // 8192 bf16 (4096 floats): W2 A-frags [mb*2+kb][lane][8]
#define OFF_PACK  6656     // float4 refs [set][b][j] = (x,y,z,|r|^2) (131072 floats)
#define OFF_IDX   137728   // int knn idx [b][n][32] (524288 ints)

// sentinel key = key(d=+inf, idx=4095) = 0x7F800000*4096 + 4095
#define KSENT 8761733287935.0

typedef __attribute__((ext_vector_type(8))) short bf16x8;
typedef __attribute__((ext_vector_type(4))) float f32x4;

static __device__ __forceinline__ unsigned short f2bf(float f) {  // RNE
  unsigned u = __float_as_uint(f);
  unsigned r = u + 0x7FFFu + ((u >> 16) & 1u);
  return (unsigned short)(r >> 16);
}

__global__ __launch_bounds__(256) void prep_kernel(
    const float* __restrict__ p1, const float* __restrict__ p2,
    const float* __restrict__ w0, const float* __restrict__ b0, const float* __restrict__ g0,
    const float* __restrict__ be0, const float* __restrict__ m0, const float* __restrict__ v0,
    const float* __restrict__ w1, const float* __restrict__ b1, const float* __restrict__ g1,
    const float* __restrict__ be1, const float* __restrict__ m1, const float* __restrict__ v1,
    const float* __restrict__ w2, const float* __restrict__ b2, const float* __restrict__ g2,
    const float* __restrict__ be2, const float* __restrict__ m2, const float* __restrict__ v2,
    float* __restrict__ ws) {
  int gid = blockIdx.x * 256 + threadIdx.x;
  if (gid < 2 * BB * NN) {   // pack refs with |r|^2
    int set = gid >> 14;
    int rem = gid & (BB * NN - 1);
    int b = rem >> 12, j = rem & (NN - 1);
    const float* p = set ? p2 : p1;
    float x = p[(b * 3 + 0) * NN + j];
    float y = p[(b * 3 + 1) * NN + j];
    float z = p[(b * 3 + 2) * NN + j];
    ((float4*)(ws + OFF_PACK))[gid] = make_float4(x, y, z, x * x + y * y + z * z);
  }
  if (gid < 256) {                         // W0S[c][4] fp32
    int c = gid >> 2, f = gid & 3;
    float s = g0[c] / sqrtf(v0[c] + 1e-3f);
    ws[OFF_W0S + gid] = w0[c * 4 + f] * s;
  } else if (gid < 320) {                  // B0F
    int c = gid - 256;
    float s = g0[c] / sqrtf(v0[c] + 1e-3f);
    ws[OFF_B0F + c] = (b0[c] - m0[c]) * s + be0[c];
  } else if (gid < 384) {                  // B1
    int o = gid - 320;
    float s = g1[o] / sqrtf(v1[o] + 1e-3f);
    ws[OFF_B1 + o] = (b1[o] - m1[o]) * s + be1[o];
  } else if (gid < 512) {                  // B2
    int o = gid - 384;
    float s = g2[o] / sqrtf(v2[o] + 1e-3f);
    ws[OFF_B2 + o] = (b2[o] - m2[o]) * s + be2[o];
  } else if (gid < 4608) {                 // W1 B-frags bf16: B[k=c][n=o]
    int e = gid - 512;
    int f = e >> 9, rem = e & 511, l = rem >> 3, j = rem & 7;
    int nb = f & 3, kb = f >> 2;
    int o = nb * 16 + (l & 15);
    int c = kb * 32 + (l >> 4) * 8 + j;
    float s = g1[o] / sqrtf(v1[o] + 1e-3f);
    ((unsigned short*)ws)[OFF_W1F * 2 + e] = f2bf(w1[o * 64 + c] * s);
  } else if (gid < 12800) {                // W2 A-frags bf16: A[m=o][k=c]
    int e = gid - 4608;
    int f = e >> 9, rem = e & 511, l = rem >> 3, j = rem & 7;
    int mb = f >> 1, kb = f & 1;
    int o = mb * 16 + (l & 15);
    int c = kb * 32 + (l >> 4) * 8 + j;
    float s = g2[o] / sqrtf(v2[o] + 1e-3f);
    ((unsigned short*)ws)[OFF_W2F * 2 + e] = f2bf(w2[o * 64 + c] * s);
  }
}

__device__ __forceinline__ float distf(float qx, float qy, float qz, float qq,
                                       const float4& rv) {
  // pinned op order: bitwise-identical d everywhere
  float dt = fmaf(qx, rv.x, fmaf(qy, rv.y, qz * rv.z));
  return fmaxf(fmaf(-2.f, dt, qq + rv.w), 0.f);   // >=0 so d_bits is order-monotone
}

#define CEU(x, y) { unsigned lo_ = min(x, y); y = max(x, y); x = lo_; }

__device__ __forceinline__ void ins16u(unsigned (&bd)[16], unsigned t) {
#pragma unroll
  for (int i = 0; i < 16; ++i) { unsigned lo = min(t, bd[i]); t = max(t, bd[i]); bd[i] = lo; }
}

__device__ __forceinline__ void ins16d(double (&bd)[16], double t) {
#pragma unroll
  for (int i = 0; i < 16; ++i) { double lo = fmin(t, bd[i]); t = fmax(t, bd[i]); bd[i] = lo; }
}

// grid: 512 blocks (set|chunk|b) x 512 threads (8 ref-split waves x 64 queries).
// Pass 1 (UNGATED, full-rate u32 network): sorted top-16 d_bits values/split.
// Merge 8 lists (wave 0) -> exact 16th-smallest T per query (w/ multiplicity).
// Pass 2: rescan, push idx of d_bits<=T (LDS atomic; superset of true top-16).
// Final: exact f64 keys d_bits*4096+idx on ~17 cands (idx-ascending ties).
// u32 CE = 2cyc vs f64 CE = 4cyc (R12 PMC: f64 network was ~60% of knn).
__global__ __launch_bounds__(512) void knn_kernel(const float* __restrict__ p1,
                                                  const float4* __restrict__ pkall,
                                                  int* __restrict__ idx_out) {
  __shared__ unsigned skeys[512 * 17];        // 34.8 KB sorted u32 d_bits
  __shared__ unsigned sthr[64];               // T per query
  __shared__ int scnt[64];                    // candidate counts
  __shared__ unsigned short cand[64][34];     // candidate idx lists

  const int tid = threadIdx.x;
  const int lane = tid & 63;
  const int wv = __builtin_amdgcn_readfirstlane(tid >> 6);  // split 0..7, SGPR
  const int set = blockIdx.x & 1;
  const int chunk = (blockIdx.x >> 1) & 63;
  const int b = blockIdx.x >> 7;
  const int n = (chunk << 6) | lane;

  const float qx = p1[(b * 3 + 0) * NN + n];
  const float qy = p1[(b * 3 + 1) * NN + n];
  const float qz = p1[(b * 3 + 2) * NN + n];
  const float qq = qx * qx + qy * qy + qz * qz;

  const float4* __restrict__ pk = pkall + (size_t)(set * BB + b) * NN;
  const int j0 = wv << 9;             // 512 refs per split

  // ---- pass 1: exact top-16 d_bits values, ungated fixed-cost network ----
  unsigned a[16];
#pragma unroll
  for (int i = 0; i < 16; ++i) a[i] = 0xFFFFFFFFu;

#pragma unroll 2
  for (int jb = j0; jb < j0 + 512; jb += 8) {
    unsigned k[8];
#pragma unroll
    for (int r = 0; r < 8; ++r) k[r] = __float_as_uint(distf(qx, qy, qz, qq, pk[jb + r]));
    // ---- sort8 ascending (Batcher odd-even, 19 CE, u32 full-rate) ----
    CEU(k[0], k[1]); CEU(k[2], k[3]); CEU(k[4], k[5]); CEU(k[6], k[7]);
    CEU(k[0], k[2]); CEU(k[1], k[3]); CEU(k[4], k[6]); CEU(k[5], k[7]);
    CEU(k[1], k[2]); CEU(k[5], k[6]);
    CEU(k[0], k[4]); CEU(k[1], k[5]); CEU(k[2], k[6]); CEU(k[3], k[7]);
    CEU(k[2], k[4]); CEU(k[3], k[5]);
    CEU(k[1], k[2]); CEU(k[3], k[4]); CEU(k[5], k[6]);
    // ---- halver: keep 16 smallest of a(16)+k(8); result bitonic ----
#pragma unroll
    for (int j = 0; j < 8; ++j) a[8 + j] = min(a[8 + j], k[7 - j]);
    // ---- bitonic merge16 ascending (4 layers x 8 CE) ----
    CEU(a[0], a[8]);  CEU(a[1], a[9]);  CEU(a[2], a[10]); CEU(a[3], a[11]);
    CEU(a[4], a[12]); CEU(a[5], a[13]); CEU(a[6], a[14]); CEU(a[7], a[15]);
    CEU(a[0], a[4]);  CEU(a[1], a[5]);  CEU(a[2], a[6]);  CEU(a[3], a[7]);
    CEU(a[8], a[12]); CEU(a[9], a[13]); CEU(a[10], a[14]); CEU(a[11], a[15]);
    CEU(a[0], a[2]);  CEU(a[1], a[3]);  CEU(a[4], a[6]);  CEU(a[5], a[7]);
    CEU(a[8], a[10]); CEU(a[9], a[11]); CEU(a[12], a[14]); CEU(a[13], a[15]);
    CEU(a[0], a[1]);  CEU(a[2], a[3]);  CEU(a[4], a[5]);  CEU(a[6], a[7]);
    CEU(a[8], a[9]);  CEU(a[10], a[11]); CEU(a[12], a[13]); CEU(a[14], a[15]);
  }

#pragma unroll
  for (int i = 0; i < 16; ++i) skeys[tid * 17 + i] = a[i];
  if (tid < 64) scnt[tid] = 0;
  __syncthreads();

  // ---- merge 8 sorted value-lists (wave 0) -> T = exact 16th-smallest ----
  if (tid < 64) {
    unsigned md[16];
#pragma unroll
    for (int i = 0; i < 16; ++i) md[i] = skeys[tid * 17 + i];
#pragma unroll 1
    for (int s = 1; s < 8; ++s) {
      int base = ((s << 6) | tid) * 17;
#pragma unroll 1
      for (int i = 0; i < 16; ++i) {
        unsigned t = skeys[base + i];
        if (t >= md[15]) break;   // sorted: rest can't change value-multiset
        ins16u(md, t);
      }
    }
    sthr[tid] = md[15];
  }
  __syncthreads();

  // ---- pass 2: rescan, push idx of all candidates with d_bits <= T ----
  const unsigned T = sthr[lane];
#pragma unroll 2
  for (int jb = j0; jb < j0 + 512; jb += 8) {
    unsigned k[8];
#pragma unroll
    for (int r = 0; r < 8; ++r) k[r] = __float_as_uint(distf(qx, qy, qz, qq, pk[jb + r]));
#pragma unroll
    for (int r = 0; r < 8; ++r) {
      if (k[r] <= T) {
        int slot = atomicAdd(&scnt[lane], 1);
        if (slot < 34) cand[lane][slot] = (unsigned short)(jb + r);
      }
    }
  }
  __syncthreads();

  // ---- final: exact (d_bits, idx) top-16 over ~16-17 candidates (wave 0) ----
  if (tid < 64) {
    int c = scnt[tid]; if (c > 34) c = 34;
    double bd[16];
#pragma unroll
    for (int i = 0; i < 16; ++i) bd[i] = KSENT;
#pragma unroll 1
    for (int i = 0; i < c; ++i) {
      int idx = cand[tid][i];
      float d = distf(qx, qy, qz, qq, pk[idx]);
      double key = fma((double)__float_as_uint(d), 4096.0, (double)idx);
      ins16d(bd, key);
    }
    const int nq = (chunk << 6) | tid;
    const int ob = (((b << 12) | nq) << 5) + (set << 4);
#pragma unroll
    for (int i = 0; i < 16; ++i) {
      unsigned db = (unsigned)(bd[i] * 0x1p-12);              // d_bits
      int idx = (int)(bd[i] - (double)db * 4096.0);           // exact low 12 bits
      idx_out[ob + i] = idx;
    }
  }
}

// grid: 4096 blocks x 256 (4 waves); wave = 1 query x 32 kk positions.
// Layer0 fp32 VALU -> bf16 -> LDS transpose; layers 1&2 on MFMA bf16.
// UNCHANGED this round: with knn dropping below it, this kernel's counters
// surface in the next profile (its dur ~105us vs ~10us issue model is the
// session's open mystery).
__global__ __launch_bounds__(256) void fusion_kernel(
    const float* __restrict__ p1, const float* __restrict__ ws,
    const float4* __restrict__ pkall, const int* __restrict__ knn_idx,
    float* __restrict__ out) {
  __shared__ __align__(16) unsigned short hbuf[4][32][72];  // [wave][pos][ch] bf16
  __shared__ float sscore[4][32];

  const int tid = threadIdx.x;
  const int l = tid & 63;
  const int wv = tid >> 6;
  const int wid = blockIdx.x * 4 + wv;     // 0..16383
  const int pbase = wid << 5;
  const int b = pbase >> 17;
  const int n = (pbase >> 5) & (NN - 1);
  const int kk = l & 31;
  const int half = l >> 5;

  // wave-uniform query
  const float qx = p1[(b * 3 + 0) * NN + n];
  const float qy = p1[(b * 3 + 1) * NN + n];
  const float qz = p1[(b * 3 + 2) * NN + n];

  // neighbor of position kk
  const int set = kk >> 4;
  const int id = knn_idx[pbase + kk] & (NN - 1);
  const float4 rv = pkall[(size_t)(set * BB + b) * NN + id];
  const float rx = rv.x - qx, ry = rv.y - qy, rz = rv.z - qz;
  const float dist = sqrtf(fmaxf(rx * rx + ry * ry + rz * rz, 1e-12f));

  // resident W1 B-frags (8 x 16B, coalesced, L1-hot)
  const bf16x8* w1f = (const bf16x8*)(ws + OFF_W1F);
  bf16x8 w1r[8];
#pragma unroll
  for (int f = 0; f < 8; ++f) w1r[f] = w1f[f * 64 + l];

  // ---- layer 0 (fp32 VALU): this lane computes 32 of 64 channels ----
  {
    const int cb = half * 32;
    const float4* w0 = (const float4*)(ws + OFF_W0S);
    float b0v[32];
#pragma unroll
    for (int q = 0; q < 8; ++q) {
      float4 bb = ((const float4*)(ws + OFF_B0F))[half * 8 + q];
      b0v[4 * q] = bb.x; b0v[4 * q + 1] = bb.y; b0v[4 * q + 2] = bb.z; b0v[4 * q + 3] = bb.w;
    }
    unsigned pk2[16];
#pragma unroll
    for (int i = 0; i < 32; i += 2) {
      float4 wa = w0[cb + i], wb = w0[cb + i + 1];
      float ha = fmaxf(fmaf(wa.x, rx, fmaf(wa.y, ry, fmaf(wa.z, rz, fmaf(wa.w, dist, b0v[i])))), 0.f);
      float hb = fmaxf(fmaf(wb.x, rx, fmaf(wb.y, ry, fmaf(wb.z, rz, fmaf(wb.w, dist, b0v[i + 1])))), 0.f);
      pk2[i >> 1] = ((unsigned)f2bf(hb) << 16) | (unsigned)f2bf(ha);
    }
    uint4* dst = (uint4*)&hbuf[wv][kk][cb];
    dst[0] = make_uint4(pk2[0], pk2[1], pk2[2], pk2[3]);
    dst[1] = make_uint4(pk2[4], pk2[5], pk2[6], pk2[7]);
    dst[2] = make_uint4(pk2[8], pk2[9], pk2[10], pk2[11]);
    dst[3] = make_uint4(pk2[12], pk2[13], pk2[14], pk2[15]);
  }
  __syncthreads();   // fence 1: h0 writes -> A-frag reads

  // ---- layer 1: D[pos][o] = h0 . W1 (MFMA), C init = bias1[col] ----
  f32x4 c1[2][4];
  {
    float b1v[4];
#pragma unroll
    for (int nb = 0; nb < 4; ++nb) b1v[nb] = ws[OFF_B1 + nb * 16 + (l & 15)];
#pragma unroll
    for (int mb = 0; mb < 2; ++mb)
#pragma unroll
      for (int nb = 0; nb < 4; ++nb) {
        c1[mb][nb][0] = b1v[nb]; c1[mb][nb][1] = b1v[nb];
        c1[mb][nb][2] = b1v[nb]; c1[mb][nb][3] = b1v[nb];
      }
  }
  bf16x8 a1[2][2];
#pragma unroll
  for (int mb = 0; mb < 2; ++mb)
#pragma unroll
    for (int kb = 0; kb < 2; ++kb)
      a1[mb][kb] = *(const bf16x8*)&hbuf[wv][mb * 16 + (l & 15)][kb * 32 + (l >> 4) * 8];
#pragma unroll
  for (int mb = 0; mb < 2; ++mb)
#pragma unroll
    for (int nb = 0; nb < 4; ++nb)
#pragma unroll
      for (int kb = 0; kb < 2; ++kb)
        c1[mb][nb] = __builtin_amdgcn_mfma_f32_16x16x32_bf16(a1[mb][kb], w1r[kb * 4 + nb],
                                                             c1[mb][nb], 0, 0, 0);

  // epilogue: relu -> bf16 -> scatter back into hbuf (h1, same [pos][ch] layout)
#pragma unroll
  for (int mb = 0; mb < 2; ++mb)
#pragma unroll
    for (int nb = 0; nb < 4; ++nb) {
      const int ch = nb * 16 + (l & 15);
#pragma unroll
      for (int r = 0; r < 4; ++r) {
        float h = fmaxf(c1[mb][nb][r], 0.f);
        hbuf[wv][mb * 16 + (l >> 4) * 4 + r][ch] = f2bf(h);
      }
    }
  __syncthreads();   // fence 2: h1 writes -> B-frag reads

  // ---- layer 2: D2^T = W2 . h1^T, bias-as-C-init, running channel max ----
  bf16x8 b2f[2][2];
#pragma unroll
  for (int nb = 0; nb < 2; ++nb)
#pragma unroll
    for (int kb = 0; kb < 2; ++kb)
      b2f[nb][kb] = *(const bf16x8*)&hbuf[wv][nb * 16 + (l & 15)][kb * 32 + (l >> 4) * 8];

  const bf16x8* w2f = (const bf16x8*)(ws + OFF_W2F);
  f32x4 rmax[2];
  rmax[0][0] = rmax[0][1] = rmax[0][2] = rmax[0][3] = -INFINITY;
  rmax[1] = rmax[0];
#pragma unroll
  for (int mb = 0; mb < 8; ++mb) {
    bf16x8 a0 = w2f[(mb * 2 + 0) * 64 + l];
    bf16x8 a1_ = w2f[(mb * 2 + 1) * 64 + l];
    float4 bb = ((const float4*)(ws + OFF_B2))[mb * 4 + (l >> 4)];
    f32x4 cini; cini[0] = bb.x; cini[1] = bb.y; cini[2] = bb.z; cini[3] = bb.w;
#pragma unroll
    for (int nb = 0; nb < 2; ++nb) {
      f32x4 c = __builtin_amdgcn_mfma_f32_16x16x32_bf16(a0, b2f[nb][0], cini, 0, 0, 0);
      c = __builtin_amdgcn_mfma_f32_16x16x32_bf16(a1_, b2f[nb][1], c, 0, 0, 0);
#pragma unroll
      for (int r = 0; r < 4; ++r) rmax[nb][r] = fmaxf(rmax[nb][r], c[r]);
    }
  }

  // reduce rows (channels) -> score per position; relu commutes with max
#pragma unroll
  for (int nb = 0; nb < 2; ++nb) {
    float m = fmaxf(fmaxf(rmax[nb][0], rmax[nb][1]), fmaxf(rmax[nb][2], rmax[nb][3]));
    m = fmaxf(m, __shfl_xor(m, 16));
    m = fmaxf(m, __shfl_xor(m, 32));
    m = fmaxf(m, 0.f);
    if ((l >> 4) == 0) sscore[wv][nb * 16 + l] = m;
  }
  __syncthreads();   // fence 3: score writes -> score reads

  // ---- softmax over 32 kk + weighted sum of neighbor coords ----
  float sc = sscore[wv][kk];
  float gm = sc;
#pragma unroll
  for (int off = 16; off > 0; off >>= 1) gm = fmaxf(gm, __shfl_xor(gm, off));
  float e = __expf(sc - gm);
  float es = e, ex = e * rv.x, ey = e * rv.y, ez = e * rv.z;
#pragma unroll
  for (int off = 16; off > 0; off >>= 1) {
    es += __shfl_xor(es, off);
    ex += __shfl_xor(ex, off);
    ey += __shfl_xor(ey, off);
    ez += __shfl_xor(ez, off);
  }
  if (l == 0) {
    float inv = 1.f / es;
    out[(b * 3 + 0) * NN + n] = ex * inv;
    out[(b * 3 + 1) * NN + n] = ey * inv;
    out[(b * 3 + 2) * NN + n] = ez * inv;
  }
}

extern "C" void kernel_launch(void* const* d_in, const int* in_sizes, int n_in,
                              void* d_out, int out_size, void* d_ws, size_t ws_size,
                              hipStream_t stream) {
  const float* p1 = (const float*)d_in[0];
  const float* p2 = (const float*)d_in[1];
  float* ws = (float*)d_ws;
  float* out = (float*)d_out;

  prep_kernel<<<128, 256, 0, stream>>>(
      p1, p2,
      (const float*)d_in[3],  (const float*)d_in[4],  (const float*)d_in[5],
      (const float*)d_in[6],  (const float*)d_in[7],  (const float*)d_in[8],
      (const float*)d_in[9],  (const float*)d_in[10], (const float*)d_in[11],
      (const float*)d_in[12], (const float*)d_in[13], (const float*)d_in[14],
      (const float*)d_in[15], (const float*)d_in[16], (const float*)d_in[17],
      (const float*)d_in[18], (const float*)d_in[19], (const float*)d_in[20],
      ws);
  knn_kernel<<<512, 512, 0, stream>>>(p1, (const float4*)(ws + OFF_PACK),
                                      (int*)(ws + OFF_IDX));
  fusion_kernel<<<4096, 256, 0, stream>>>(p1, ws, (const float4*)(ws + OFF_PACK),
                                          (const int*)(ws + OFF_IDX), out);
}

// Round 14
// 229.510 us; speedup vs baseline: 1.1105x; 1.1105x over previous
//
#include <hip/hip_runtime.h>
#include <math.h>

#define BB 4
#define NN 4096

// workspace layout (float offsets)
#define OFF_W0S   0        // 256 fp32: w0*s0 [c][4]
#define OFF_B0F   256      // 64 fp32
#define OFF_B1    320      // 64 fp32
#define OFF_B2    384      // 128 fp32
#define OFF_W1F   512      // 4096 bf16 (2048 floats): W1 B-frags [kb*4+nb][lane][8]
#define OFF_W2F   2560     // 8192 bf16 (4096 floats): W2 A-frags [mb*2+kb][lane][8]
#define OFF_PACK  6656     // float4 refs [set][b][j] = (x,y,z,|r|^2) (131072 floats)
#define OFF_IDX   137728   // int knn idx [b][n][32] (524288 ints)

// sentinel key = key(d=+inf, idx=4095) = 0x7F800000*4096 + 4095
#define KSENT 8761733287935.0

typedef __attribute__((ext_vector_type(8))) short bf16x8;
typedef __attribute__((ext_vector_type(4))) float f32x4;

static __device__ __forceinline__ unsigned short f2bf(float f) {  // RNE
  unsigned u = __float_as_uint(f);
  unsigned r = u + 0x7FFFu + ((u >> 16) & 1u);
  return (unsigned short)(r >> 16);
}

__global__ __launch_bounds__(256) void prep_kernel(
    const float* __restrict__ p1, const float* __restrict__ p2,
    const float* __restrict__ w0, const float* __restrict__ b0, const float* __restrict__ g0,
    const float* __restrict__ be0, const float* __restrict__ m0, const float* __restrict__ v0,
    const float* __restrict__ w1, const float* __restrict__ b1, const float* __restrict__ g1,
    const float* __restrict__ be1, const float* __restrict__ m1, const float* __restrict__ v1,
    const float* __restrict__ w2, const float* __restrict__ b2, const float* __restrict__ g2,
    const float* __restrict__ be2, const float* __restrict__ m2, const float* __restrict__ v2,
    float* __restrict__ ws) {
  int gid = blockIdx.x * 256 + threadIdx.x;
  if (gid < 2 * BB * NN) {   // pack refs with |r|^2
    int set = gid >> 14;
    int rem = gid & (BB * NN - 1);
    int b = rem >> 12, j = rem & (NN - 1);
    const float* p = set ? p2 : p1;
    float x = p[(b * 3 + 0) * NN + j];
    float y = p[(b * 3 + 1) * NN + j];
    float z = p[(b * 3 + 2) * NN + j];
    ((float4*)(ws + OFF_PACK))[gid] = make_float4(x, y, z, x * x + y * y + z * z);
  }
  if (gid < 256) {                         // W0S[c][4] fp32
    int c = gid >> 2, f = gid & 3;
    float s = g0[c] / sqrtf(v0[c] + 1e-3f);
    ws[OFF_W0S + gid] = w0[c * 4 + f] * s;
  } else if (gid < 320) {                  // B0F
    int c = gid - 256;
    float s = g0[c] / sqrtf(v0[c] + 1e-3f);
    ws[OFF_B0F + c] = (b0[c] - m0[c]) * s + be0[c];
  } else if (gid < 384) {                  // B1
    int o = gid - 320;
    float s = g1[o] / sqrtf(v1[o] + 1e-3f);
    ws[OFF_B1 + o] = (b1[o] - m1[o]) * s + be1[o];
  } else if (gid < 512) {                  // B2
    int o = gid - 384;
    float s = g2[o] / sqrtf(v2[o] + 1e-3f);
    ws[OFF_B2 + o] = (b2[o] - m2[o]) * s + be2[o];
  } else if (gid < 4608) {                 // W1 B-frags bf16: B[k=c][n=o]
    int e = gid - 512;
    int f = e >> 9, rem = e & 511, l = rem >> 3, j = rem & 7;
    int nb = f & 3, kb = f >> 2;
    int o = nb * 16 + (l & 15);
    int c = kb * 32 + (l >> 4) * 8 + j;
    float s = g1[o] / sqrtf(v1[o] + 1e-3f);
    ((unsigned short*)ws)[OFF_W1F * 2 + e] = f2bf(w1[o * 64 + c] * s);
  } else if (gid < 12800) {                // W2 A-frags bf16: A[m=o][k=c]
    int e = gid - 4608;
    int f = e >> 9, rem = e & 511, l = rem >> 3, j = rem & 7;
    int mb = f >> 1, kb = f & 1;
    int o = mb * 16 + (l & 15);
    int c = kb * 32 + (l >> 4) * 8 + j;
    float s = g2[o] / sqrtf(v2[o] + 1e-3f);
    ((unsigned short*)ws)[OFF_W2F * 2 + e] = f2bf(w2[o * 64 + c] * s);
  }
}

__device__ __forceinline__ float distf(float qx, float qy, float qz, float qq,
                                       const float4& rv) {
  // pinned op order: bitwise-identical d everywhere
  float dt = fmaf(qx, rv.x, fmaf(qy, rv.y, qz * rv.z));
  return fmaxf(fmaf(-2.f, dt, qq + rv.w), 0.f);   // >=0 so d_bits is order-monotone
}

#define CED(x, y) { double lo_ = fmin(x, y); y = fmax(x, y); x = lo_; }

__device__ __forceinline__ void ins16d(double (&bd)[16], double t) {
#pragma unroll
  for (int i = 0; i < 16; ++i) { double lo = fmin(t, bd[i]); t = fmax(t, bd[i]); bd[i] = lo; }
}

// grid: 512 blocks (set|chunk|b) x 512 threads (8 ref-split waves x 64 queries).
// R12 structure verbatim (proven 111.6us): single pass, UNGATED fixed-cost
// batch network on exact f64 keys key = d_bits*4096 + idx (bit-exact d order,
// idx-ascending ties). Threshold-rescan variants lose (R10: 140, R13: 126).
__global__ __launch_bounds__(512) void knn_kernel(const float* __restrict__ p1,
                                                  const float4* __restrict__ pkall,
                                                  int* __restrict__ idx_out) {
  __shared__ double skeys[512 * 17];   // 69.6 KB, pad 17 for bank spread

  const int tid = threadIdx.x;
  const int lane = tid & 63;
  const int wv = __builtin_amdgcn_readfirstlane(tid >> 6);  // split 0..7, SGPR
  const int set = blockIdx.x & 1;
  const int chunk = (blockIdx.x >> 1) & 63;
  const int b = blockIdx.x >> 7;
  const int n = (chunk << 6) | lane;

  const float qx = p1[(b * 3 + 0) * NN + n];
  const float qy = p1[(b * 3 + 1) * NN + n];
  const float qz = p1[(b * 3 + 2) * NN + n];
  const float qq = qx * qx + qy * qy + qz * qz;

  const float4* __restrict__ pk = pkall + (size_t)(set * BB + b) * NN;
  const int j0 = wv << 9;             // 512 refs per split

  double a[16];
#pragma unroll
  for (int i = 0; i < 16; ++i) a[i] = KSENT;

#pragma unroll 2
  for (int jb = j0; jb < j0 + 512; jb += 8) {
    const double jbd = (double)jb;
    double k[8];
#pragma unroll
    for (int r = 0; r < 8; ++r) {
      float d = distf(qx, qy, qz, qq, pk[jb + r]);
      k[r] = fma((double)__float_as_uint(d), 4096.0, jbd + (double)r);
    }
    // ---- sort8 ascending (Batcher odd-even, 19 CE) ----
    CED(k[0], k[1]); CED(k[2], k[3]); CED(k[4], k[5]); CED(k[6], k[7]);
    CED(k[0], k[2]); CED(k[1], k[3]); CED(k[4], k[6]); CED(k[5], k[7]);
    CED(k[1], k[2]); CED(k[5], k[6]);
    CED(k[0], k[4]); CED(k[1], k[5]); CED(k[2], k[6]); CED(k[3], k[7]);
    CED(k[2], k[4]); CED(k[3], k[5]);
    CED(k[1], k[2]); CED(k[3], k[4]); CED(k[5], k[6]);
    // ---- halver: keep 16 smallest of a(16)+k(8); result bitonic ----
#pragma unroll
    for (int j = 0; j < 8; ++j) a[8 + j] = fmin(a[8 + j], k[7 - j]);
    // ---- bitonic merge16 ascending (4 layers x 8 CE) ----
    CED(a[0], a[8]);  CED(a[1], a[9]);  CED(a[2], a[10]); CED(a[3], a[11]);
    CED(a[4], a[12]); CED(a[5], a[13]); CED(a[6], a[14]); CED(a[7], a[15]);
    CED(a[0], a[4]);  CED(a[1], a[5]);  CED(a[2], a[6]);  CED(a[3], a[7]);
    CED(a[8], a[12]); CED(a[9], a[13]); CED(a[10], a[14]); CED(a[11], a[15]);
    CED(a[0], a[2]);  CED(a[1], a[3]);  CED(a[4], a[6]);  CED(a[5], a[7]);
    CED(a[8], a[10]); CED(a[9], a[11]); CED(a[12], a[14]); CED(a[13], a[15]);
    CED(a[0], a[1]);  CED(a[2], a[3]);  CED(a[4], a[5]);  CED(a[6], a[7]);
    CED(a[8], a[9]);  CED(a[10], a[11]); CED(a[12], a[13]); CED(a[14], a[15]);
  }

#pragma unroll
  for (int i = 0; i < 16; ++i) skeys[tid * 17 + i] = a[i];
  __syncthreads();

  // ---- merge 8 sorted lists (wave 0), write final indices ----
  if (tid < 64) {
    double md[16];
#pragma unroll
    for (int i = 0; i < 16; ++i) md[i] = skeys[tid * 17 + i];
#pragma unroll 1
    for (int s = 1; s < 8; ++s) {
      int base = ((s << 6) | tid) * 17;
#pragma unroll 1
      for (int i = 0; i < 16; ++i) {
        double t = skeys[base + i];
        if (t >= md[15]) break;   // sorted: rest can't qualify
        ins16d(md, t);
      }
    }
    const int nq = (chunk << 6) | tid;
    const int ob = (((b << 12) | nq) << 5) + (set << 4);
#pragma unroll
    for (int i = 0; i < 16; ++i) {
      unsigned db = (unsigned)(md[i] * 0x1p-12);              // d_bits
      int idx = (int)(md[i] - (double)db * 4096.0);           // exact low 12 bits
      idx_out[ob + i] = idx;
    }
  }
}

// grid: 4096 blocks x 256 (4 waves); wave = 1 query x 32 kk positions.
// Layer0 fp32 VALU -> bf16 -> LDS transpose; layers 1&2 on MFMA bf16.
// NEW this round: __launch_bounds__(256,4) caps VGPR<=128 (4 waves/EU ->
// 16 waves/CU); b0v register array removed (bias via wave-uniform s_loads).
// Theory: unconstrained VGPR alloc of the big unrolled body dropped occupancy
// to <=3 waves/SIMD -> the ~10x stall vs issue model.
__global__ __launch_bounds__(256, 4) void fusion_kernel(
    const float* __restrict__ p1, const float* __restrict__ ws,
    const float4* __restrict__ pkall, const int* __restrict__ knn_idx,
    float* __restrict__ out) {
  __shared__ __align__(16) unsigned short hbuf[4][32][72];  // [wave][pos][ch] bf16
  __shared__ float sscore[4][32];

  const int tid = threadIdx.x;
  const int l = tid & 63;
  const int wv = tid >> 6;
  const int wid = blockIdx.x * 4 + wv;     // 0..16383
  const int pbase = wid << 5;
  const int b = pbase >> 17;
  const int n = (pbase >> 5) & (NN - 1);
  const int kk = l & 31;
  const int half = l >> 5;

  // wave-uniform query
  const float qx = p1[(b * 3 + 0) * NN + n];
  const float qy = p1[(b * 3 + 1) * NN + n];
  const float qz = p1[(b * 3 + 2) * NN + n];

  // neighbor of position kk
  const int set = kk >> 4;
  const int id = knn_idx[pbase + kk] & (NN - 1);
  const float4 rv = pkall[(size_t)(set * BB + b) * NN + id];
  const float rx = rv.x - qx, ry = rv.y - qy, rz = rv.z - qz;
  const float dist = sqrtf(fmaxf(rx * rx + ry * ry + rz * rz, 1e-12f));

  // resident W1 B-frags (8 x 16B, coalesced, L1-hot)
  const bf16x8* w1f = (const bf16x8*)(ws + OFF_W1F);
  bf16x8 w1r[8];
#pragma unroll
  for (int f = 0; f < 8; ++f) w1r[f] = w1f[f * 64 + l];

  // ---- layer 0 (fp32 VALU): this lane computes 32 of 64 channels ----
  {
    const int cb = half * 32;
    const float4* w0 = (const float4*)(ws + OFF_W0S);
    const float* b0p = ws + OFF_B0F + cb;   // wave-uniform-per-half scalar reads
    unsigned pk2[16];
#pragma unroll
    for (int i = 0; i < 32; i += 2) {
      float4 wa = w0[cb + i], wb = w0[cb + i + 1];
      float ha = fmaxf(fmaf(wa.x, rx, fmaf(wa.y, ry, fmaf(wa.z, rz, fmaf(wa.w, dist, b0p[i])))), 0.f);
      float hb = fmaxf(fmaf(wb.x, rx, fmaf(wb.y, ry, fmaf(wb.z, rz, fmaf(wb.w, dist, b0p[i + 1])))), 0.f);
      pk2[i >> 1] = ((unsigned)f2bf(hb) << 16) | (unsigned)f2bf(ha);
    }
    uint4* dst = (uint4*)&hbuf[wv][kk][cb];
    dst[0] = make_uint4(pk2[0], pk2[1], pk2[2], pk2[3]);
    dst[1] = make_uint4(pk2[4], pk2[5], pk2[6], pk2[7]);
    dst[2] = make_uint4(pk2[8], pk2[9], pk2[10], pk2[11]);
    dst[3] = make_uint4(pk2[12], pk2[13], pk2[14], pk2[15]);
  }
  __syncthreads();   // fence 1: h0 writes -> A-frag reads

  // ---- layer 1: D[pos][o] = h0 . W1 (MFMA), C init = bias1[col] ----
  f32x4 c1[2][4];
  {
    float b1v[4];
#pragma unroll
    for (int nb = 0; nb < 4; ++nb) b1v[nb] = ws[OFF_B1 + nb * 16 + (l & 15)];
#pragma unroll
    for (int mb = 0; mb < 2; ++mb)
#pragma unroll
      for (int nb = 0; nb < 4; ++nb) {
        c1[mb][nb][0] = b1v[nb]; c1[mb][nb][1] = b1v[nb];
        c1[mb][nb][2] = b1v[nb]; c1[mb][nb][3] = b1v[nb];
      }
  }
  bf16x8 a1[2][2];
#pragma unroll
  for (int mb = 0; mb < 2; ++mb)
#pragma unroll
    for (int kb = 0; kb < 2; ++kb)
      a1[mb][kb] = *(const bf16x8*)&hbuf[wv][mb * 16 + (l & 15)][kb * 32 + (l >> 4) * 8];
#pragma unroll
  for (int mb = 0; mb < 2; ++mb)
#pragma unroll
    for (int nb = 0; nb < 4; ++nb)
#pragma unroll
      for (int kb = 0; kb < 2; ++kb)
        c1[mb][nb] = __builtin_amdgcn_mfma_f32_16x16x32_bf16(a1[mb][kb], w1r[kb * 4 + nb],
                                                             c1[mb][nb], 0, 0, 0);

  // epilogue: relu -> bf16 -> scatter back into hbuf (h1, same [pos][ch] layout)
#pragma unroll
  for (int mb = 0; mb < 2; ++mb)
#pragma unroll
    for (int nb = 0; nb < 4; ++nb) {
      const int ch = nb * 16 + (l & 15);
#pragma unroll
      for (int r = 0; r < 4; ++r) {
        float h = fmaxf(c1[mb][nb][r], 0.f);
        hbuf[wv][mb * 16 + (l >> 4) * 4 + r][ch] = f2bf(h);
      }
    }
  __syncthreads();   // fence 2: h1 writes -> B-frag reads

  // ---- layer 2: D2^T = W2 . h1^T, bias-as-C-init, running channel max ----
  bf16x8 b2f[2][2];
#pragma unroll
  for (int nb = 0; nb < 2; ++nb)
#pragma unroll
    for (int kb = 0; kb < 2; ++kb)
      b2f[nb][kb] = *(const bf16x8*)&hbuf[wv][nb * 16 + (l & 15)][kb * 32 + (l >> 4) * 8];

  const bf16x8* w2f = (const bf16x8*)(ws + OFF_W2F);
  f32x4 rmax[2];
  rmax[0][0] = rmax[0][1] = rmax[0][2] = rmax[0][3] = -INFINITY;
  rmax[1] = rmax[0];
#pragma unroll 2
  for (int mb = 0; mb < 8; ++mb) {
    bf16x8 a0 = w2f[(mb * 2 + 0) * 64 + l];
    bf16x8 a1_ = w2f[(mb * 2 + 1) * 64 + l];
    float4 bb = ((const float4*)(ws + OFF_B2))[mb * 4 + (l >> 4)];
    f32x4 cini; cini[0] = bb.x; cini[1] = bb.y; cini[2] = bb.z; cini[3] = bb.w;
#pragma unroll
    for (int nb = 0; nb < 2; ++nb) {
      f32x4 c = __builtin_amdgcn_mfma_f32_16x16x32_bf16(a0, b2f[nb][0], cini, 0, 0, 0);
      c = __builtin_amdgcn_mfma_f32_16x16x32_bf16(a1_, b2f[nb][1], c, 0, 0, 0);
#pragma unroll
      for (int r = 0; r < 4; ++r) rmax[nb][r] = fmaxf(rmax[nb][r], c[r]);
    }
  }

  // reduce rows (channels) -> score per position; relu commutes with max
#pragma unroll
  for (int nb = 0; nb < 2; ++nb) {
    float m = fmaxf(fmaxf(rmax[nb][0], rmax[nb][1]), fmaxf(rmax[nb][2], rmax[nb][3]));
    m = fmaxf(m, __shfl_xor(m, 16));
    m = fmaxf(m, __shfl_xor(m, 32));
    m = fmaxf(m, 0.f);
    if ((l >> 4) == 0) sscore[wv][nb * 16 + l] = m;
  }
  __syncthreads();   // fence 3: score writes -> score reads

  // ---- softmax over 32 kk + weighted sum of neighbor coords ----
  float sc = sscore[wv][kk];
  float gm = sc;
#pragma unroll
  for (int off = 16; off > 0; off >>= 1) gm = fmaxf(gm, __shfl_xor(gm, off));
  float e = __expf(sc - gm);
  float es = e, ex = e * rv.x, ey = e * rv.y, ez = e * rv.z;
#pragma unroll
  for (int off = 16; off > 0; off >>= 1) {
    es += __shfl_xor(es, off);
    ex += __shfl_xor(ex, off);
    ey += __shfl_xor(ey, off);
    ez += __shfl_xor(ez, off);
  }
  if (l == 0) {
    float inv = 1.f / es;
    out[(b * 3 + 0) * NN + n] = ex * inv;
    out[(b * 3 + 1) * NN + n] = ey * inv;
    out[(b * 3 + 2) * NN + n] = ez * inv;
  }
}

extern "C" void kernel_launch(void* const* d_in, const int* in_sizes, int n_in,
                              void* d_out, int out_size, void* d_ws, size_t ws_size,
                              hipStream_t stream) {
  const float* p1 = (const float*)d_in[0];
  const float* p2 = (const float*)d_in[1];
  float* ws = (float*)d_ws;
  float* out = (float*)d_out;

  prep_kernel<<<128, 256, 0, stream>>>(
      p1, p2,
      (const float*)d_in[3],  (const float*)d_in[4],  (const float*)d_in[5],
      (const float*)d_in[6],  (const float*)d_in[7],  (const float*)d_in[8],
      (const float*)d_in[9],  (const float*)d_in[10], (const float*)d_in[11],
      (const float*)d_in[12], (const float*)d_in[13], (const float*)d_in[14],
      (const float*)d_in[15], (const float*)d_in[16], (const float*)d_in[17],
      (const float*)d_in[18], (const float*)d_in[19], (const float*)d_in[20],
      ws);
  knn_kernel<<<512, 512, 0, stream>>>(p1, (const float4*)(ws + OFF_PACK),
                                      (int*)(ws + OFF_IDX));
  fusion_kernel<<<4096, 256, 0, stream>>>(p1, ws, (const float4*)(ws + OFF_PACK),
                                          (const int*)(ws + OFF_IDX), out);
}